// Round 1
// baseline (631.344 us; speedup 1.0000x reference)
//
#include <hip/hip_runtime.h>

#define N_NODES 50000
#define N_EDGES 800000
#define NODE_DIM 128
#define EDGE_DIM 64
#define HIDDEN 256
#define K_E 320   // 2*NODE_DIM + EDGE_DIM
#define K_N 192   // NODE_DIM + EDGE_DIM

typedef __attribute__((ext_vector_type(8))) short bf16x8;
typedef __attribute__((ext_vector_type(4))) float f32x4;
typedef unsigned short u16;
typedef unsigned int u32;

__device__ inline u16 f2bf(float f) {
  u32 u = __builtin_bit_cast(u32, f);
  u += 0x7fffu + ((u >> 16) & 1u);
  return (u16)(u >> 16);
}

__device__ inline void st_bf4(u16* p, float4 v) {
  ushort4 r;
  r.x = f2bf(v.x); r.y = f2bf(v.y); r.z = f2bf(v.z); r.w = f2bf(v.w);
  *reinterpret_cast<ushort4*>(p) = r;
}

// ---------------- weight prep: f32 [K][N] -> bf16 [N][K] ----------------
__global__ void prep_weights(const float* __restrict__ We1, const float* __restrict__ We2,
                             const float* __restrict__ Wn1, const float* __restrict__ Wn2,
                             u16* __restrict__ we1t, u16* __restrict__ we2t,
                             u16* __restrict__ wn1t, u16* __restrict__ wn2t) {
  const int stride = gridDim.x * blockDim.x;
  const int tid = blockIdx.x * blockDim.x + threadIdx.x;
  for (int i = tid; i < HIDDEN * K_E; i += stride) {
    int n = i / K_E, k = i % K_E;
    we1t[i] = f2bf(We1[k * HIDDEN + n]);
  }
  for (int i = tid; i < EDGE_DIM * HIDDEN; i += stride) {
    int n = i / HIDDEN, k = i % HIDDEN;
    we2t[i] = f2bf(We2[k * EDGE_DIM + n]);
  }
  for (int i = tid; i < HIDDEN * K_N; i += stride) {
    int n = i / K_N, k = i % K_N;
    wn1t[i] = f2bf(Wn1[k * HIDDEN + n]);
  }
  for (int i = tid; i < NODE_DIM * HIDDEN; i += stride) {
    int n = i / HIDDEN, k = i % HIDDEN;
    wn2t[i] = f2bf(Wn2[k * NODE_DIM + n]);
  }
}

// ---------------- edge MLP + scatter ----------------
#define SA_E 328  // 320 + 8 pad (bank-friendly: +4 banks/row)
#define SH   264  // 256 + 8 pad

__global__ __launch_bounds__(256) void edge_kernel(
    const float* __restrict__ nf, const float* __restrict__ ef,
    const int* __restrict__ src, const int* __restrict__ dst,
    const u16* __restrict__ w1, const float* __restrict__ b1,
    const u16* __restrict__ w2, const float* __restrict__ b2,
    float* __restrict__ e_sum, float* __restrict__ degf,
    float* __restrict__ out_edge)
{
  __shared__ u16 A[64 * SA_E];   // concat tile, later aliased as hidden H
  __shared__ int sidx[64], didx[64];
  const int tid = threadIdx.x;
  const int e0 = blockIdx.x * 64;   // N_EDGES % 64 == 0

  if (tid < 64) { sidx[tid] = src[e0 + tid]; didx[tid] = dst[e0 + tid]; }
  __syncthreads();

  const float4* nf4 = reinterpret_cast<const float4*>(nf);
  const float4* ef4 = reinterpret_cast<const float4*>(ef);
  float4* oe4 = reinterpret_cast<float4*>(out_edge);

  // stage src halves: cols 0..127
  {
    int row = tid >> 5, c4 = tid & 31;
    #pragma unroll
    for (int p = 0; p < 8; ++p, row += 8) {
      float4 v = nf4[(size_t)sidx[row] * 32 + c4];
      st_bf4(&A[row * SA_E + c4 * 4], v);
    }
  }
  // stage edge features: cols 128..191, fused passthrough to out
  {
    #pragma unroll
    for (int p = 0; p < 4; ++p) {
      int idx = p * 256 + tid;
      int row = idx >> 4, c4 = idx & 15;
      size_t g = (size_t)(e0 + row) * 16 + c4;
      float4 v = ef4[g];
      oe4[g] = v;
      st_bf4(&A[row * SA_E + 128 + c4 * 4], v);
    }
  }
  // stage dst halves: cols 192..319
  {
    int row = tid >> 5, c4 = tid & 31;
    #pragma unroll
    for (int p = 0; p < 8; ++p, row += 8) {
      float4 v = nf4[(size_t)didx[row] * 32 + c4];
      st_bf4(&A[row * SA_E + 192 + c4 * 4], v);
    }
  }
  if (tid < 64) degf[didx[tid]] = 1.0f;   // benign races: all write 1.0
  __syncthreads();

  const int wave = tid >> 6, lane = tid & 63;
  const int lr = lane & 15;          // A row / B col within 16-tile
  const int lk = (lane >> 4) * 8;    // k sub-offset

  // layer 1: [64 x 320] @ [320 x 256], each wave owns 64 output cols
  f32x4 acc[4][4] = {};
  for (int kb = 0; kb < K_E / 32; ++kb) {
    const int ko = kb * 32 + lk;
    bf16x8 a[4], b[4];
    #pragma unroll
    for (int mt = 0; mt < 4; ++mt)
      a[mt] = *reinterpret_cast<const bf16x8*>(&A[(mt * 16 + lr) * SA_E + ko]);
    #pragma unroll
    for (int nt = 0; nt < 4; ++nt)
      b[nt] = *reinterpret_cast<const bf16x8*>(&w1[(size_t)(wave * 64 + nt * 16 + lr) * K_E + ko]);
    #pragma unroll
    for (int mt = 0; mt < 4; ++mt)
      #pragma unroll
      for (int nt = 0; nt < 4; ++nt)
        acc[mt][nt] = __builtin_amdgcn_mfma_f32_16x16x32_bf16(a[mt], b[nt], acc[mt][nt], 0, 0, 0);
  }
  __syncthreads();   // all layer-1 A reads done before aliasing as H

  u16* H = A;
  #pragma unroll
  for (int mt = 0; mt < 4; ++mt)
    #pragma unroll
    for (int nt = 0; nt < 4; ++nt) {
      int col = wave * 64 + nt * 16 + lr;
      float bias = b1[col];
      #pragma unroll
      for (int j = 0; j < 4; ++j) {
        int row = mt * 16 + (lane >> 4) * 4 + j;
        float h = acc[mt][nt][j] + bias;
        H[row * SH + col] = f2bf(h > 0.f ? h : 0.f);
      }
    }
  __syncthreads();

  // layer 2: H [64 x 256] @ [256 x 64]; wave owns 16 rows, all 64 cols
  f32x4 acc2[4] = {};
  for (int kb = 0; kb < HIDDEN / 32; ++kb) {
    const int ko = kb * 32 + lk;
    bf16x8 a = *reinterpret_cast<const bf16x8*>(&H[(wave * 16 + lr) * SH + ko]);
    #pragma unroll
    for (int nt = 0; nt < 4; ++nt) {
      bf16x8 b = *reinterpret_cast<const bf16x8*>(&w2[(size_t)(nt * 16 + lr) * HIDDEN + ko]);
      acc2[nt] = __builtin_amdgcn_mfma_f32_16x16x32_bf16(a, b, acc2[nt], 0, 0, 0);
    }
  }
  #pragma unroll
  for (int nt = 0; nt < 4; ++nt) {
    int col = nt * 16 + lr;
    float bias = b2[col];
    #pragma unroll
    for (int j = 0; j < 4; ++j) {
      int row = wave * 16 + (lane >> 4) * 4 + j;
      atomicAdd(&e_sum[(size_t)didx[row] * 64 + col], acc2[nt][j] + bias);
    }
  }
}

// ---------------- node MLP + degree gate ----------------
#define SA_N 200  // 192 + 8 pad

__global__ __launch_bounds__(256) void node_kernel(
    const float* __restrict__ nf, const float* __restrict__ e_sum,
    const float* __restrict__ degf,
    const u16* __restrict__ w1, const float* __restrict__ b1,
    const u16* __restrict__ w2, const float* __restrict__ b2,
    float* __restrict__ hout)
{
  __shared__ u16 A[64 * SH];   // max(64*SA_N, 64*SH)
  const int tid = threadIdx.x;
  const int n0 = blockIdx.x * 64;

  const float4* nf4 = reinterpret_cast<const float4*>(nf);
  const float4* es4 = reinterpret_cast<const float4*>(e_sum);

  // stage node rows: cols 0..127 (clamped for tail block)
  {
    int row = tid >> 5, c4 = tid & 31;
    #pragma unroll
    for (int p = 0; p < 8; ++p, row += 8) {
      int rg = min(n0 + row, N_NODES - 1);
      float4 v = nf4[(size_t)rg * 32 + c4];
      st_bf4(&A[row * SA_N + c4 * 4], v);
    }
  }
  // stage e_sum rows: cols 128..191
  {
    #pragma unroll
    for (int p = 0; p < 4; ++p) {
      int idx = p * 256 + tid;
      int row = idx >> 4, c4 = idx & 15;
      int rg = min(n0 + row, N_NODES - 1);
      float4 v = es4[(size_t)rg * 16 + c4];
      st_bf4(&A[row * SA_N + 128 + c4 * 4], v);
    }
  }
  __syncthreads();

  const int wave = tid >> 6, lane = tid & 63;
  const int lr = lane & 15;
  const int lk = (lane >> 4) * 8;

  // layer 1: [64 x 192] @ [192 x 256]
  f32x4 acc[4][4] = {};
  for (int kb = 0; kb < K_N / 32; ++kb) {
    const int ko = kb * 32 + lk;
    bf16x8 a[4], b[4];
    #pragma unroll
    for (int mt = 0; mt < 4; ++mt)
      a[mt] = *reinterpret_cast<const bf16x8*>(&A[(mt * 16 + lr) * SA_N + ko]);
    #pragma unroll
    for (int nt = 0; nt < 4; ++nt)
      b[nt] = *reinterpret_cast<const bf16x8*>(&w1[(size_t)(wave * 64 + nt * 16 + lr) * K_N + ko]);
    #pragma unroll
    for (int mt = 0; mt < 4; ++mt)
      #pragma unroll
      for (int nt = 0; nt < 4; ++nt)
        acc[mt][nt] = __builtin_amdgcn_mfma_f32_16x16x32_bf16(a[mt], b[nt], acc[mt][nt], 0, 0, 0);
  }
  __syncthreads();

  u16* H = A;
  #pragma unroll
  for (int mt = 0; mt < 4; ++mt)
    #pragma unroll
    for (int nt = 0; nt < 4; ++nt) {
      int col = wave * 64 + nt * 16 + lr;
      float bias = b1[col];
      #pragma unroll
      for (int j = 0; j < 4; ++j) {
        int row = mt * 16 + (lane >> 4) * 4 + j;
        float h = acc[mt][nt][j] + bias;
        H[row * SH + col] = f2bf(h > 0.f ? h : 0.f);
      }
    }
  __syncthreads();

  // layer 2: H [64 x 256] @ [256 x 128]; wave owns 16 rows, all 128 cols
  f32x4 acc2[8] = {};
  for (int kb = 0; kb < HIDDEN / 32; ++kb) {
    const int ko = kb * 32 + lk;
    bf16x8 a = *reinterpret_cast<const bf16x8*>(&H[(wave * 16 + lr) * SH + ko]);
    #pragma unroll
    for (int nt = 0; nt < 8; ++nt) {
      bf16x8 b = *reinterpret_cast<const bf16x8*>(&w2[(size_t)(nt * 16 + lr) * HIDDEN + ko]);
      acc2[nt] = __builtin_amdgcn_mfma_f32_16x16x32_bf16(a, b, acc2[nt], 0, 0, 0);
    }
  }
  #pragma unroll
  for (int nt = 0; nt < 8; ++nt) {
    int col = nt * 16 + lr;
    float bias = b2[col];
    #pragma unroll
    for (int j = 0; j < 4; ++j) {
      int row = wave * 16 + (lane >> 4) * 4 + j;
      int rg = n0 + row;
      if (rg < N_NODES) {
        float v = acc2[nt][j] + bias;
        hout[(size_t)rg * NODE_DIM + col] =
            (degf[rg] > 0.f) ? v : nf[(size_t)rg * NODE_DIM + col];
      }
    }
  }
}

// ---------------- launcher ----------------
extern "C" void kernel_launch(void* const* d_in, const int* in_sizes, int n_in,
                              void* d_out, int out_size, void* d_ws, size_t ws_size,
                              hipStream_t stream) {
  const float* nf  = (const float*)d_in[0];
  const float* ef  = (const float*)d_in[1];
  const int*   src = (const int*)d_in[2];
  const int*   dst = (const int*)d_in[3];
  const float* We1 = (const float*)d_in[4];
  const float* be1 = (const float*)d_in[5];
  const float* We2 = (const float*)d_in[6];
  const float* be2 = (const float*)d_in[7];
  const float* Wn1 = (const float*)d_in[8];
  const float* bn1 = (const float*)d_in[9];
  const float* Wn2 = (const float*)d_in[10];
  const float* bn2 = (const float*)d_in[11];

  char* ws = (char*)d_ws;
  float* e_sum = (float*)ws;                       // 50000*64*4 = 12,800,000 B
  float* degf  = (float*)(ws + 12800000);          // 50000*4   = 200,000 B
  u16*  we1t   = (u16*)(ws + 13000000);            // 256*320*2 = 163,840 B
  u16*  we2t   = (u16*)(ws + 13163840);            // 64*256*2  = 32,768 B
  u16*  wn1t   = (u16*)(ws + 13196608);            // 256*192*2 = 98,304 B
  u16*  wn2t   = (u16*)(ws + 13294912);            // 128*256*2 = 65,536 B

  float* hout = (float*)d_out;
  float* out_edge = hout + (size_t)N_NODES * NODE_DIM;

  hipMemsetAsync(ws, 0, 13000000, stream);  // zero e_sum + degf
  prep_weights<<<128, 256, 0, stream>>>(We1, We2, Wn1, Wn2, we1t, we2t, wn1t, wn2t);
  edge_kernel<<<N_EDGES / 64, 256, 0, stream>>>(nf, ef, src, dst, we1t, be1, we2t, be2,
                                                e_sum, degf, out_edge);
  node_kernel<<<(N_NODES + 63) / 64, 256, 0, stream>>>(nf, e_sum, degf, wn1t, bn1,
                                                       wn2t, bn2, hout);
}